// Round 22
// baseline (119.612 us; speedup 1.0000x reference)
//
#include <hip/hip_runtime.h>
#include <hip/hip_bf16.h>
#include <stdint.h>

// GPT2Attention: S=2048 E=1024 H=16 d=64 T=4096 past=2048, f32 in/out.
// Round 22: attn prefetch depth-2 on the r18/r21 structure: Ks[3]/Vs[3]
// (66.4KB LDS -> 2 blocks/CU), stage tile i+2, exact counted waits via
// per-thread load FIFO: steady vmcnt(6), tails 4/2/0. Everything else
// byte-identical to r21 (118.5us best: dbuf GEMMs, mega-prep, affinity).

#define S_LEN 2048
#define E_DIM 1024
#define NHEAD 16
#define HDIM  64
#define T_LEN 4096
#define PASTL 2048

typedef __bf16 bf16x8 __attribute__((ext_vector_type(8)));
typedef __bf16 bf16x4 __attribute__((ext_vector_type(4)));
typedef float  f32x4  __attribute__((ext_vector_type(4)));

static __device__ __forceinline__ f32x4 mfma_bf16(bf16x8 a, bf16x8 b, f32x4 c) {
  return __builtin_amdgcn_mfma_f32_16x16x32_bf16(a, b, c, 0, 0, 0);
}

// RNE float -> bf16 bits (values finite)
static __device__ __forceinline__ unsigned int f2bf(float f) {
  union { float f; unsigned int u; } v; v.f = f;
  unsigned int u = v.u;
  return (u + 0x7fffu + ((u >> 16) & 1u)) >> 16;
}

static __device__ __forceinline__ float bf2f(unsigned short u) {
  union { unsigned int u; float f; } v; v.u = (unsigned int)u << 16;
  return v.f;
}

#define GLOBAL_LOAD_LDS16(gptr, lptr)                                              \
  __builtin_amdgcn_global_load_lds(                                                \
      (const __attribute__((address_space(1))) unsigned int*)(gptr),               \
      (__attribute__((address_space(3))) unsigned int*)(lptr), 16, 0, 0)

// ---------------------------------------------------------------- mega-prep
__global__ __launch_bounds__(256) void prep_kernel(
    const float* __restrict__ past, const float* __restrict__ x,
    const float* __restrict__ W1, const float* __restrict__ W2,
    float* __restrict__ cache, unsigned short* __restrict__ kb,
    unsigned short* __restrict__ xb, unsigned short* __restrict__ w1t,
    unsigned short* __restrict__ w2t, unsigned short* __restrict__ vtb) {
  __shared__ float tile[64][65];
  const int bid = blockIdx.x;
  const int tid = threadIdx.x;
  const int tx = tid & 63, ty = tid >> 6;

  if (bid < 512) {
    // past_v transpose: h = bid>>5, t-tile = bid&31
    const int h = bid >> 5;
    const int t0 = (bid & 31) * 64;
    const float* in = past + (size_t)(NHEAD + h) * T_LEN * HDIM;
    unsigned short* outp = vtb + (size_t)h * HDIM * T_LEN;
#pragma unroll
    for (int r = 0; r < 64; r += 4)
      tile[r + ty][tx] = in[(size_t)(t0 + r + ty) * HDIM + tx];
    __syncthreads();
#pragma unroll
    for (int r = 0; r < 64; r += 4)
      outp[(size_t)(r + ty) * T_LEN + t0 + tx] = f2bf(tile[tx][r + ty]);
  } else if (bid < 1536) {
    // weight transpose-convert
    const float* in;
    unsigned short* outp;
    int rows, cols, c0, r0;
    if (bid < 1280) {
      int u = bid - 512;
      in = W1; outp = w1t; rows = 1024; cols = 3072;
      c0 = (u % 48) * 64; r0 = (u / 48) * 64;
    } else {
      int u = bid - 1280;
      in = W2; outp = w2t; rows = 1024; cols = 1024;
      c0 = (u & 15) * 64; r0 = (u >> 4) * 64;
    }
#pragma unroll
    for (int r = 0; r < 64; r += 4)
      tile[r + ty][tx] = in[(size_t)(r0 + r + ty) * cols + c0 + tx];
    __syncthreads();
#pragma unroll
    for (int r = 0; r < 64; r += 4)
      outp[(size_t)(c0 + r + ty) * rows + r0 + tx] = f2bf(tile[tx][r + ty]);
  } else {
    const int n4p = (2 * NHEAD * PASTL * HDIM) / 4;  // 1,048,576
    const int n4x = (S_LEN * E_DIM) / 4;             // 524,288
    for (int i = (bid - 1536) * 256 + tid; i < n4p + n4x; i += 2048 * 256) {
      if (i < n4p) {
        int e = i * 4;
        int d = e & 63;
        int t = (e >> 6) & (PASTL - 1);
        int hh = (e >> 17) & (NHEAD - 1);
        int kv = e >> 21;
        size_t full = (((size_t)kv * NHEAD + hh) * T_LEN + t) * HDIM + d;
        float4 v = *(const float4*)(past + full);
        *(float4*)(cache + full) = v;
        if (kv == 0) {
          ushort4 u;
          u.x = f2bf(v.x); u.y = f2bf(v.y); u.z = f2bf(v.z); u.w = f2bf(v.w);
          *(ushort4*)(kb + full) = u;
        }
      } else {
        int j = i - n4p;
        float4 v = ((const float4*)x)[j];
        ushort4 u;
        u.x = f2bf(v.x); u.y = f2bf(v.y); u.z = f2bf(v.z); u.w = f2bf(v.w);
        ((ushort4*)xb)[j] = u;
      }
    }
  }
}

// ---------------------------------------------------------------- GEMM (B^T)
// 64x128 tile, 4 waves (2x2 of 32x64), BK=64, acc[2][4], double-buffered
// K-loop (r21). 1D grid, XCD-clustered. MODE 0: c_attn epilogue. MODE 1: f32.
template <int MODE>
__global__ __launch_bounds__(256) void gemm_bt_kernel(
    const unsigned short* __restrict__ A, const unsigned short* __restrict__ Bt,
    const float* __restrict__ bias, int K,
    float* __restrict__ out_f32, unsigned short* __restrict__ qb,
    float* __restrict__ cache_k, float* __restrict__ cache_v,
    unsigned short* __restrict__ kb, unsigned short* __restrict__ vtb) {
  __shared__ alignas(16) unsigned short As[2][64 * 64];
  __shared__ alignas(16) unsigned short Bs[2][128 * 64];
  const int NPX = (MODE == 0) ? 3 : 1;
  const int bid = blockIdx.x;
  const int xcd = bid & 7;
  const int loc = bid >> 3;
  const int n_idx = xcd * NPX + loc % NPX;
  const int m_idx = loc / NPX;
  const int m0 = m_idx * 64, n0 = n_idx * 128;

  const int tid = threadIdx.x;
  const int lane = tid & 63;
  const int w = tid >> 6;
  const int wm = w >> 1, wn = w & 1;
  const int lr = lane & 15;
  const int lg = lane >> 4;

  f32x4 acc[2][4];
#pragma unroll
  for (int i = 0; i < 2; ++i)
#pragma unroll
    for (int j = 0; j < 4; ++j) acc[i][j] = f32x4{0.f, 0.f, 0.f, 0.f};

  const int srow = tid >> 3;
  const int sseg = (tid & 7) ^ (srow & 7);
  const unsigned short* ga0 = A + (size_t)(m0 + srow) * K + sseg * 8;
  const unsigned short* gb0 = Bt + (size_t)(n0 + srow) * K + sseg * 8;

  auto stage = [&](int b, int k0) {
    GLOBAL_LOAD_LDS16(ga0 + k0, (char*)As[b] + tid * 16);
    GLOBAL_LOAD_LDS16(ga0 + (size_t)32 * K + k0, (char*)As[b] + 4096 + tid * 16);
#pragma unroll
    for (int j = 0; j < 4; ++j)
      GLOBAL_LOAD_LDS16(gb0 + (size_t)(32 * j) * K + k0,
                        (char*)Bs[b] + j * 4096 + tid * 16);
  };

  const int NKS = K >> 6;  // 16
  stage(0, 0);
  int cur = 0;
  for (int i = 0; i < NKS; ++i) {
    asm volatile("s_waitcnt vmcnt(0)" ::: "memory");
    __builtin_amdgcn_s_barrier();
    __builtin_amdgcn_sched_barrier(0);
    if (i + 1 < NKS) stage(cur ^ 1, (i + 1) * 64);  // flies under compute

#pragma unroll
    for (int kk = 0; kk < 2; ++kk) {
      bf16x8 af[2], bfr[4];
#pragma unroll
      for (int mi = 0; mi < 2; ++mi) {
        int row = wm * 32 + mi * 16 + lr;
        int slot = (kk * 4 + lg) ^ (row & 7);
        af[mi] = *reinterpret_cast<const bf16x8*>((const char*)As[cur] + row * 128 + slot * 16);
      }
#pragma unroll
      for (int ni = 0; ni < 4; ++ni) {
        int row = wn * 64 + ni * 16 + lr;
        int slot = (kk * 4 + lg) ^ (row & 7);
        bfr[ni] = *reinterpret_cast<const bf16x8*>((const char*)Bs[cur] + row * 128 + slot * 16);
      }
#pragma unroll
      for (int mi = 0; mi < 2; ++mi)
#pragma unroll
        for (int ni = 0; ni < 4; ++ni)
          acc[mi][ni] = mfma_bf16(af[mi], bfr[ni], acc[mi][ni]);
    }
    cur ^= 1;
  }

#pragma unroll
  for (int ni = 0; ni < 4; ++ni) {
    int n = n0 + wn * 64 + ni * 16 + lr;
    float bv = bias[n];
#pragma unroll
    for (int mi = 0; mi < 2; ++mi) {
      int mbase = m0 + wm * 32 + mi * 16 + lg * 4;
      float v4[4];
#pragma unroll
      for (int r = 0; r < 4; ++r) v4[r] = acc[mi][ni][r] + bv;
      if (MODE == 0) {
        if (n < E_DIM) {
#pragma unroll
          for (int r = 0; r < 4; ++r)
            qb[(size_t)(mbase + r) * E_DIM + n] = f2bf(v4[r] * 0.18033688f);
        } else if (n < 2 * E_DIM) {
          int e = n - E_DIM;
          size_t base = ((size_t)(e >> 6) * T_LEN + (PASTL + mbase)) * HDIM + (e & 63);
#pragma unroll
          for (int r = 0; r < 4; ++r) {
            cache_k[base + (size_t)r * HDIM] = v4[r];
            kb[base + (size_t)r * HDIM] = f2bf(v4[r]);
          }
        } else {
          int e = n - 2 * E_DIM;
          int hh = e >> 6, d = e & 63;
          size_t base = ((size_t)hh * T_LEN + (PASTL + mbase)) * HDIM + d;
#pragma unroll
          for (int r = 0; r < 4; ++r) cache_v[base + (size_t)r * HDIM] = v4[r];
          ushort4 u;
          u.x = f2bf(v4[0]); u.y = f2bf(v4[1]);
          u.z = f2bf(v4[2]); u.w = f2bf(v4[3]);
          *(ushort4*)(vtb + ((size_t)hh * HDIM + d) * T_LEN + PASTL + mbase) = u;
        }
      } else {
#pragma unroll
        for (int r = 0; r < 4; ++r)
          out_f32[(size_t)(mbase + r) * E_DIM + n] = v4[r];
      }
    }
  }
}

// ---------------------------------------------------------------- attention
// r18 structure + depth-2 prefetch: Ks[3]/Vs[3], stage tile i+2. Per-thread
// load FIFO: K(i),V(i),K(i+1),V(i+1),K(i+2),... -> exact counted waits:
// phase1 (need K(i)): vmcnt(6) steady / vmcnt(2) last tile.
// phase2 (need V(i)): vmcnt(6) if i+2<NT, vmcnt(4) if i+1<NT, else vmcnt(0).
// Race-safety: buffer (i+2)%3's previous occupant (tile i-1) is fully read
// before the barrier that precedes its overwrite.
__global__ __launch_bounds__(256) void attn_kernel(
    const unsigned short* __restrict__ qb, const unsigned short* __restrict__ kb,
    const unsigned short* __restrict__ vt,
    unsigned short* __restrict__ o_part, float* __restrict__ l_part) {
  __shared__ alignas(16) unsigned short Ks[3][64 * 64];
  __shared__ alignas(16) unsigned short Vs[3][64 * 64];
  __shared__ alignas(16) __bf16 p_lds[4][32][72];
  const int fid = blockIdx.x;  // 0..895
  const int h = (fid & 7) + ((fid >= 448) ? 8 : 0);
  const int g = (fid >> 3) - ((fid >= 448) ? 56 : 0);  // 0..55
  int x, c;
  if (g < 24) { x = g / 3; c = g - 3 * x; }
  else { int g2 = g - 24; x = 8 + (g2 >> 2); c = g2 & 3; }

  const int tid = threadIdx.x;
  const int w = tid >> 6;
  const int lane = tid & 63;
  const int lr = lane & 15;
  const int lg = lane >> 4;
  const int qb0 = x * 128;
  const int q0 = qb0 + w * 32;

  const unsigned short* qr0 = qb + (size_t)(q0 + lr) * E_DIM + h * HDIM + lg * 8;
  const unsigned short* qr1 = qb + (size_t)(q0 + 16 + lr) * E_DIM + h * HDIM + lg * 8;
  const bf16x8 qf00 = *reinterpret_cast<const bf16x8*>(qr0);
  const bf16x8 qf01 = *reinterpret_cast<const bf16x8*>(qr0 + 32);
  const bf16x8 qf10 = *reinterpret_cast<const bf16x8*>(qr1);
  const bf16x8 qf11 = *reinterpret_cast<const bf16x8*>(qr1 + 32);

  const unsigned short* kh = kb + (size_t)h * T_LEN * HDIM;
  const unsigned short* vh = vt + (size_t)h * HDIM * T_LEN;

  const int srow = tid >> 3;  // 0..31
  const int sseg = (tid & 7) ^ (srow & 7);
  const unsigned short* ksrc = kh + (size_t)srow * HDIM + sseg * 8;
  const unsigned short* vsrc = vh + (size_t)srow * T_LEN + sseg * 8;

  f32x4 o[2][4];
  float lsum[2][2];
#pragma unroll
  for (int sb = 0; sb < 2; ++sb) {
    lsum[sb][0] = lsum[sb][1] = 0.f;
#pragma unroll
    for (int jd = 0; jd < 4; ++jd) o[sb][jd] = f32x4{0.f, 0.f, 0.f, 0.f};
  }

  const int jmaxq = q0 + PASTL;
  const int NTfull = 34 + 2 * x;
  const int tb = c * 16;
  const int te = (tb + 16 < NTfull) ? tb + 16 : NTfull;
  const int NT = te - tb;   // >= 2 always
  const int tbeg = tb * 64;

  auto stageK = [&](int b, int t0) {
    GLOBAL_LOAD_LDS16(ksrc + (size_t)t0 * HDIM, (char*)Ks[b] + tid * 16);
    GLOBAL_LOAD_LDS16(ksrc + (size_t)(t0 + 32) * HDIM, (char*)Ks[b] + 4096 + tid * 16);
  };
  auto stageV = [&](int b, int t0) {
    GLOBAL_LOAD_LDS16(vsrc + t0, (char*)Vs[b] + tid * 16);
    GLOBAL_LOAD_LDS16(vsrc + t0 + (size_t)32 * T_LEN, (char*)Vs[b] + 4096 + tid * 16);
  };

  // prologue: tiles 0 and 1 (NT >= 2 guaranteed)
  stageK(0, tbeg);
  stageV(0, tbeg);
  stageK(1, tbeg + 64);
  stageV(1, tbeg + 64);

  int cur = 0, nx2 = 2;  // nx2 = (i+2)%3
  int t0 = tbeg;
  for (int i = 0; i < NT; ++i, t0 += 64) {
    const bool m1 = (i + 1 < NT), m2 = (i + 2 < NT);
    // ---- phase 1: need K(i); FIFO leaves V(i)[,K(i+1),V(i+1)] outstanding ----
    if (m1) {
      asm volatile("s_waitcnt vmcnt(6)" ::: "memory");
    } else {
      asm volatile("s_waitcnt vmcnt(2)" ::: "memory");
    }
    __builtin_amdgcn_s_barrier();
    __builtin_amdgcn_sched_barrier(0);
    if (m2) stageK(nx2, t0 + 128);

    bf16x8 kf[4][2];
#pragma unroll
    for (int j = 0; j < 4; ++j) {
      int row = j * 16 + lr;
      int s0 = lg ^ (row & 7), s1 = (4 + lg) ^ (row & 7);
      kf[j][0] = *reinterpret_cast<const bf16x8*>((const char*)Ks[cur] + row * 128 + s0 * 16);
      kf[j][1] = *reinterpret_cast<const bf16x8*>((const char*)Ks[cur] + row * 128 + s1 * 16);
    }

    f32x4 sc[2][4];
#pragma unroll
    for (int sb = 0; sb < 2; ++sb)
#pragma unroll
      for (int j = 0; j < 4; ++j) sc[sb][j] = f32x4{0.f, 0.f, 0.f, 0.f};
    __builtin_amdgcn_s_setprio(1);
#pragma unroll
    for (int j = 0; j < 4; ++j) {
      sc[0][j] = mfma_bf16(kf[j][0], qf00, sc[0][j]);
      sc[0][j] = mfma_bf16(kf[j][1], qf01, sc[0][j]);
      sc[1][j] = mfma_bf16(kf[j][0], qf10, sc[1][j]);
      sc[1][j] = mfma_bf16(kf[j][1], qf11, sc[1][j]);
    }
    __builtin_amdgcn_s_setprio(0);

    // ---- softmax -> p_lds (per-wave private; no barrier needed) ----
    const bool partial = (t0 + 63 > jmaxq);
    const int thr = q0 + PASTL - t0 + lr;
    const int lg4 = lg * 4;
#pragma unroll
    for (int sb = 0; sb < 2; ++sb) {
#pragma unroll
      for (int j = 0; j < 4; ++j) {
        bf16x4 pk;
#pragma unroll
        for (int r = 0; r < 4; ++r) {
          float p = __builtin_amdgcn_exp2f(sc[sb][j][r]);
          if (partial && (j * 16 + lg4 + r > thr + sb * 16)) p = 0.f;
          lsum[sb][r >> 1] += p;
          pk[r] = (__bf16)p;
        }
        *reinterpret_cast<bf16x4*>(&p_lds[w][sb * 16 + lr][j * 16 + lg4]) = pk;
      }
    }
    bf16x8 pa[2][2];
#pragma unroll
    for (int sb = 0; sb < 2; ++sb) {
      pa[sb][0] = *reinterpret_cast<const bf16x8*>(&p_lds[w][sb * 16 + lr][lg * 8]);
      pa[sb][1] = *reinterpret_cast<const bf16x8*>(&p_lds[w][sb * 16 + lr][32 + lg * 8]);
    }

    // ---- phase 2: need V(i); outstanding K(i+1),V(i+1)[,K(i+2)] ----
    if (m2) {
      asm volatile("s_waitcnt vmcnt(6)" ::: "memory");
    } else if (m1) {
      asm volatile("s_waitcnt vmcnt(4)" ::: "memory");
    } else {
      asm volatile("s_waitcnt vmcnt(0)" ::: "memory");
    }
    __builtin_amdgcn_s_barrier();
    __builtin_amdgcn_sched_barrier(0);
    if (m2) stageV(nx2, t0 + 128);

    __builtin_amdgcn_s_setprio(1);
#pragma unroll
    for (int jd = 0; jd < 4; ++jd) {
      int row = jd * 16 + lr;
      int s0 = lg ^ (row & 7), s1 = (4 + lg) ^ (row & 7);
      bf16x8 vf0 = *reinterpret_cast<const bf16x8*>((const char*)Vs[cur] + row * 128 + s0 * 16);
      bf16x8 vf1 = *reinterpret_cast<const bf16x8*>((const char*)Vs[cur] + row * 128 + s1 * 16);
      o[0][jd] = mfma_bf16(pa[0][0], vf0, o[0][jd]);
      o[0][jd] = mfma_bf16(pa[0][1], vf1, o[0][jd]);
      o[1][jd] = mfma_bf16(pa[1][0], vf0, o[1][jd]);
      o[1][jd] = mfma_bf16(pa[1][1], vf1, o[1][jd]);
    }
    __builtin_amdgcn_s_setprio(0);
    cur = (cur == 2) ? 0 : cur + 1;
    nx2 = (nx2 == 2) ? 0 : nx2 + 1;
  }

  // partials: o_part[c][h][row][d] bf16, l_part[c][h][row] f32
  unsigned short* op = o_part + ((size_t)(c * NHEAD + h) * S_LEN) * HDIM;
  float* lp = l_part + (size_t)(c * NHEAD + h) * S_LEN;
#pragma unroll
  for (int sb = 0; sb < 2; ++sb) {
    float ls = lsum[sb][0] + lsum[sb][1];
    ls += __shfl_xor(ls, 16);
    ls += __shfl_xor(ls, 32);
    if (lg == 0) lp[q0 + sb * 16 + lr] = ls;
#pragma unroll
    for (int jd = 0; jd < 4; ++jd) {
#pragma unroll
      for (int r = 0; r < 4; ++r) {
        int row = q0 + sb * 16 + lg * 4 + r;
        op[(size_t)row * HDIM + jd * 16 + lr] = f2bf(o[sb][jd][r]);
      }
    }
  }
}

// Merge chunk partials (3 for rows<1024, 4 otherwise) and normalize -> ab bf16.
__global__ __launch_bounds__(256) void attn_merge_kernel(
    const unsigned short* __restrict__ o_part, const float* __restrict__ l_part,
    unsigned short* __restrict__ ab) {
  const int flat = blockIdx.x * 256 + threadIdx.x;
  const int d4 = flat & 15;
  const int row = (flat >> 4) & (S_LEN - 1);
  const int h = flat >> 15;
  const int nc = (row < 1024) ? 3 : 4;
  const size_t cstride_o = (size_t)NHEAD * S_LEN * HDIM;
  const size_t base_o = (((size_t)h * S_LEN) + row) * HDIM + d4 * 4;
  float acc[4] = {0.f, 0.f, 0.f, 0.f};
  float l = 0.f;
  for (int cc = 0; cc < nc; ++cc) {
    ushort4 u = *(const ushort4*)(o_part + cc * cstride_o + base_o);
    acc[0] += bf2f(u.x); acc[1] += bf2f(u.y);
    acc[2] += bf2f(u.z); acc[3] += bf2f(u.w);
    l += l_part[(size_t)cc * NHEAD * S_LEN + (size_t)h * S_LEN + row];
  }
  float inv = 1.f / l;
  ushort4 u;
  u.x = f2bf(acc[0] * inv);
  u.y = f2bf(acc[1] * inv);
  u.z = f2bf(acc[2] * inv);
  u.w = f2bf(acc[3] * inv);
  *(ushort4*)(ab + (size_t)row * E_DIM + h * HDIM + d4 * 4) = u;
}

// ---------------------------------------------------------------- launch

extern "C" void kernel_launch(void* const* d_in, const int* in_sizes, int n_in,
                              void* d_out, int out_size, void* d_ws, size_t ws_size,
                              hipStream_t stream) {
  (void)in_sizes; (void)n_in; (void)out_size; (void)ws_size;
  const float* x    = (const float*)d_in[0];
  const float* past = (const float*)d_in[1];
  const float* W1   = (const float*)d_in[2];
  const float* b1   = (const float*)d_in[3];
  const float* W2   = (const float*)d_in[4];
  const float* b2   = (const float*)d_in[5];

  float* out = (float*)d_out;
  float* cache_k = out + (size_t)S_LEN * E_DIM;
  float* cache_v = cache_k + (size_t)NHEAD * T_LEN * HDIM;

  // Workspace layout (42.5 MiB peak), lifetime-disjoint overlaps:
  //   [0,2)   w2t ; [2,6) qb ; [6,14) kb ; [14,22) vtb
  //   [22,26) xb -> ab ; [26,32) w1t -> o_part ; [26,42) o_part
  //   [42,42.5) l_part
  char* ws = (char*)d_ws;
  unsigned short* w2t = (unsigned short*)(ws);
  unsigned short* qb  = (unsigned short*)(ws + (size_t)(2u  << 20));
  unsigned short* kb  = (unsigned short*)(ws + (size_t)(6u  << 20));
  unsigned short* vtb = (unsigned short*)(ws + (size_t)(14u << 20));
  unsigned short* xb  = (unsigned short*)(ws + (size_t)(22u << 20));
  unsigned short* ab  = (unsigned short*)(ws + (size_t)(22u << 20));  // reuse xb
  unsigned short* w1t = (unsigned short*)(ws + (size_t)(26u << 20));
  unsigned short* o_part = (unsigned short*)(ws + (size_t)(26u << 20));  // reuse w1t
  float* l_part = (float*)(ws + (size_t)(42u << 20));

  prep_kernel<<<3584, 256, 0, stream>>>(past, x, W1, W2, cache_k, kb, xb, w1t,
                                        w2t, vtb);
  gemm_bt_kernel<0><<<768, 256, 0, stream>>>(
      xb, w1t, b1, 1024, nullptr, qb, cache_k, cache_v, kb, vtb);
  attn_kernel<<<dim3(896), 256, 0, stream>>>(qb, kb, vtb, o_part, l_part);
  attn_merge_kernel<<<(NHEAD * S_LEN * 16) / 256, 256, 0, stream>>>(o_part, l_part, ab);
  gemm_bt_kernel<1><<<256, 256, 0, stream>>>(
      ab, w2t, b2, 1024, out, nullptr, nullptr, nullptr, nullptr, nullptr);
}

// Round 23
// 118.404 us; speedup vs baseline: 1.0102x; 1.0102x over previous
//
#include <hip/hip_runtime.h>
#include <hip/hip_bf16.h>
#include <stdint.h>

// GPT2Attention: S=2048 E=1024 H=16 d=64 T=4096 past=2048, f32 in/out.
// Round 23: REVERT to r21 (best: 118.5us). r22's depth-2 attn prefetch hit the
// pre-committed failure band (62.9 >= 63-ish, LDS 67.6KB cost > pipeline gain).
// FINAL CONFIG: mega-prep (1 launch) -> dbuf XCD-clustered 64x128 GEMM<0>
// -> attn (r12-best wave code, 4-phase split-wait vmcnt(2), 896 blocks,
// fid%8==head%8 affinity) -> merge -> dbuf GEMM<1>. 5 launches total.

#define S_LEN 2048
#define E_DIM 1024
#define NHEAD 16
#define HDIM  64
#define T_LEN 4096
#define PASTL 2048

typedef __bf16 bf16x8 __attribute__((ext_vector_type(8)));
typedef __bf16 bf16x4 __attribute__((ext_vector_type(4)));
typedef float  f32x4  __attribute__((ext_vector_type(4)));

static __device__ __forceinline__ f32x4 mfma_bf16(bf16x8 a, bf16x8 b, f32x4 c) {
  return __builtin_amdgcn_mfma_f32_16x16x32_bf16(a, b, c, 0, 0, 0);
}

// RNE float -> bf16 bits (values finite)
static __device__ __forceinline__ unsigned int f2bf(float f) {
  union { float f; unsigned int u; } v; v.f = f;
  unsigned int u = v.u;
  return (u + 0x7fffu + ((u >> 16) & 1u)) >> 16;
}

static __device__ __forceinline__ float bf2f(unsigned short u) {
  union { unsigned int u; float f; } v; v.u = (unsigned int)u << 16;
  return v.f;
}

#define GLOBAL_LOAD_LDS16(gptr, lptr)                                              \
  __builtin_amdgcn_global_load_lds(                                                \
      (const __attribute__((address_space(1))) unsigned int*)(gptr),               \
      (__attribute__((address_space(3))) unsigned int*)(lptr), 16, 0, 0)

// ---------------------------------------------------------------- mega-prep
// blockIdx ranges:
//  [0,512):     past_v (t<2048) -> vtb [h][d][t] transpose (LDS tiles)
//  [512,1280):  W1 [1024][3072] -> w1t [3072][1024] bf16
//  [1280,1536): W2 [1024][1024] -> w2t [1024][1024] bf16
//  [1536,3584): grid-stride: past(t<2048,K+V)->cache f32; K half also ->kb bf16;
//               x -> xb bf16
__global__ __launch_bounds__(256) void prep_kernel(
    const float* __restrict__ past, const float* __restrict__ x,
    const float* __restrict__ W1, const float* __restrict__ W2,
    float* __restrict__ cache, unsigned short* __restrict__ kb,
    unsigned short* __restrict__ xb, unsigned short* __restrict__ w1t,
    unsigned short* __restrict__ w2t, unsigned short* __restrict__ vtb) {
  __shared__ float tile[64][65];
  const int bid = blockIdx.x;
  const int tid = threadIdx.x;
  const int tx = tid & 63, ty = tid >> 6;

  if (bid < 512) {
    // past_v transpose: h = bid>>5, t-tile = bid&31
    const int h = bid >> 5;
    const int t0 = (bid & 31) * 64;
    const float* in = past + (size_t)(NHEAD + h) * T_LEN * HDIM;
    unsigned short* outp = vtb + (size_t)h * HDIM * T_LEN;
#pragma unroll
    for (int r = 0; r < 64; r += 4)
      tile[r + ty][tx] = in[(size_t)(t0 + r + ty) * HDIM + tx];
    __syncthreads();
#pragma unroll
    for (int r = 0; r < 64; r += 4)
      outp[(size_t)(r + ty) * T_LEN + t0 + tx] = f2bf(tile[tx][r + ty]);
  } else if (bid < 1536) {
    // weight transpose-convert
    const float* in;
    unsigned short* outp;
    int rows, cols, c0, r0;
    if (bid < 1280) {
      int u = bid - 512;
      in = W1; outp = w1t; rows = 1024; cols = 3072;
      c0 = (u % 48) * 64; r0 = (u / 48) * 64;
    } else {
      int u = bid - 1280;
      in = W2; outp = w2t; rows = 1024; cols = 1024;
      c0 = (u & 15) * 64; r0 = (u >> 4) * 64;
    }
#pragma unroll
    for (int r = 0; r < 64; r += 4)
      tile[r + ty][tx] = in[(size_t)(r0 + r + ty) * cols + c0 + tx];
    __syncthreads();
#pragma unroll
    for (int r = 0; r < 64; r += 4)
      outp[(size_t)(c0 + r + ty) * rows + r0 + tx] = f2bf(tile[tx][r + ty]);
  } else {
    const int n4p = (2 * NHEAD * PASTL * HDIM) / 4;  // 1,048,576
    const int n4x = (S_LEN * E_DIM) / 4;             // 524,288
    for (int i = (bid - 1536) * 256 + tid; i < n4p + n4x; i += 2048 * 256) {
      if (i < n4p) {
        int e = i * 4;
        int d = e & 63;
        int t = (e >> 6) & (PASTL - 1);
        int hh = (e >> 17) & (NHEAD - 1);
        int kv = e >> 21;
        size_t full = (((size_t)kv * NHEAD + hh) * T_LEN + t) * HDIM + d;
        float4 v = *(const float4*)(past + full);
        *(float4*)(cache + full) = v;
        if (kv == 0) {
          ushort4 u;
          u.x = f2bf(v.x); u.y = f2bf(v.y); u.z = f2bf(v.z); u.w = f2bf(v.w);
          *(ushort4*)(kb + full) = u;
        }
      } else {
        int j = i - n4p;
        float4 v = ((const float4*)x)[j];
        ushort4 u;
        u.x = f2bf(v.x); u.y = f2bf(v.y); u.z = f2bf(v.z); u.w = f2bf(v.w);
        ((ushort4*)xb)[j] = u;
      }
    }
  }
}

// ---------------------------------------------------------------- GEMM (B^T)
// 64x128 tile, 4 waves (2x2 of 32x64), BK=64, acc[2][4], DOUBLE-BUFFERED
// K-loop (stage(next) issued after raw s_barrier; loads overlap MFMA).
// 1D grid, XCD-clustered: xcd=bid&7 owns n-panels [xcd*NPX, xcd*NPX+NPX).
// MODE 0: c_attn epilogue (24 n-panels, NPX=3). MODE 1: f32 out (8, NPX=1).
template <int MODE>
__global__ __launch_bounds__(256) void gemm_bt_kernel(
    const unsigned short* __restrict__ A, const unsigned short* __restrict__ Bt,
    const float* __restrict__ bias, int K,
    float* __restrict__ out_f32, unsigned short* __restrict__ qb,
    float* __restrict__ cache_k, float* __restrict__ cache_v,
    unsigned short* __restrict__ kb, unsigned short* __restrict__ vtb) {
  __shared__ alignas(16) unsigned short As[2][64 * 64];
  __shared__ alignas(16) unsigned short Bs[2][128 * 64];
  const int NPX = (MODE == 0) ? 3 : 1;
  const int bid = blockIdx.x;
  const int xcd = bid & 7;
  const int loc = bid >> 3;
  const int n_idx = xcd * NPX + loc % NPX;
  const int m_idx = loc / NPX;
  const int m0 = m_idx * 64, n0 = n_idx * 128;

  const int tid = threadIdx.x;
  const int lane = tid & 63;
  const int w = tid >> 6;
  const int wm = w >> 1, wn = w & 1;  // wave covers rows wm*32.., cols wn*64..
  const int lr = lane & 15;
  const int lg = lane >> 4;

  f32x4 acc[2][4];
#pragma unroll
  for (int i = 0; i < 2; ++i)
#pragma unroll
    for (int j = 0; j < 4; ++j) acc[i][j] = f32x4{0.f, 0.f, 0.f, 0.f};

  // staging: thread -> (row = tid>>3 (+32j), seg = tid&7), source pre-swizzled
  const int srow = tid >> 3;
  const int sseg = (tid & 7) ^ (srow & 7);
  const unsigned short* ga0 = A + (size_t)(m0 + srow) * K + sseg * 8;
  const unsigned short* gb0 = Bt + (size_t)(n0 + srow) * K + sseg * 8;

  auto stage = [&](int b, int k0) {
    GLOBAL_LOAD_LDS16(ga0 + k0, (char*)As[b] + tid * 16);
    GLOBAL_LOAD_LDS16(ga0 + (size_t)32 * K + k0, (char*)As[b] + 4096 + tid * 16);
#pragma unroll
    for (int j = 0; j < 4; ++j)
      GLOBAL_LOAD_LDS16(gb0 + (size_t)(32 * j) * K + k0,
                        (char*)Bs[b] + j * 4096 + tid * 16);
  };

  const int NKS = K >> 6;  // 16
  stage(0, 0);
  int cur = 0;
  for (int i = 0; i < NKS; ++i) {
    // buf[cur]'s 6 loads (issued last iter / prologue) must land; all waves
    // must be past reads of buf[cur^1] before we overwrite it.
    asm volatile("s_waitcnt vmcnt(0)" ::: "memory");
    __builtin_amdgcn_s_barrier();
    __builtin_amdgcn_sched_barrier(0);
    if (i + 1 < NKS) stage(cur ^ 1, (i + 1) * 64);  // flies under compute

#pragma unroll
    for (int kk = 0; kk < 2; ++kk) {
      bf16x8 af[2], bfr[4];
#pragma unroll
      for (int mi = 0; mi < 2; ++mi) {
        int row = wm * 32 + mi * 16 + lr;
        int slot = (kk * 4 + lg) ^ (row & 7);
        af[mi] = *reinterpret_cast<const bf16x8*>((const char*)As[cur] + row * 128 + slot * 16);
      }
#pragma unroll
      for (int ni = 0; ni < 4; ++ni) {
        int row = wn * 64 + ni * 16 + lr;
        int slot = (kk * 4 + lg) ^ (row & 7);
        bfr[ni] = *reinterpret_cast<const bf16x8*>((const char*)Bs[cur] + row * 128 + slot * 16);
      }
#pragma unroll
      for (int mi = 0; mi < 2; ++mi)
#pragma unroll
        for (int ni = 0; ni < 4; ++ni)
          acc[mi][ni] = mfma_bf16(af[mi], bfr[ni], acc[mi][ni]);
    }
    cur ^= 1;
  }

#pragma unroll
  for (int ni = 0; ni < 4; ++ni) {
    int n = n0 + wn * 64 + ni * 16 + lr;
    float bv = bias[n];
#pragma unroll
    for (int mi = 0; mi < 2; ++mi) {
      int mbase = m0 + wm * 32 + mi * 16 + lg * 4;  // 4 consecutive rows
      float v4[4];
#pragma unroll
      for (int r = 0; r < 4; ++r) v4[r] = acc[mi][ni][r] + bv;
      if (MODE == 0) {
        if (n < E_DIM) {
#pragma unroll
          for (int r = 0; r < 4; ++r)
            qb[(size_t)(mbase + r) * E_DIM + n] = f2bf(v4[r] * 0.18033688f);
        } else if (n < 2 * E_DIM) {
          int e = n - E_DIM;
          size_t base = ((size_t)(e >> 6) * T_LEN + (PASTL + mbase)) * HDIM + (e & 63);
#pragma unroll
          for (int r = 0; r < 4; ++r) {
            cache_k[base + (size_t)r * HDIM] = v4[r];
            kb[base + (size_t)r * HDIM] = f2bf(v4[r]);
          }
        } else {
          int e = n - 2 * E_DIM;
          int hh = e >> 6, d = e & 63;
          size_t base = ((size_t)hh * T_LEN + (PASTL + mbase)) * HDIM + d;
#pragma unroll
          for (int r = 0; r < 4; ++r) cache_v[base + (size_t)r * HDIM] = v4[r];
          ushort4 u;
          u.x = f2bf(v4[0]); u.y = f2bf(v4[1]);
          u.z = f2bf(v4[2]); u.w = f2bf(v4[3]);
          *(ushort4*)(vtb + ((size_t)hh * HDIM + d) * T_LEN + PASTL + mbase) = u;
        }
      } else {
#pragma unroll
        for (int r = 0; r < 4; ++r)
          out_f32[(size_t)(mbase + r) * E_DIM + n] = v4[r];
      }
    }
  }
}

// ---------------------------------------------------------------- attention
// r12-best structure: 4 waves (256 thr)/block, 32 q-rows/wave (two 16-row sb),
// KVBLK=64, swapped QK^T (mfma(K,Q)), bf16x4 P via p_lds (pad 72 — proven).
// 4-phase split-wait: stageK/stageV separate, counted vmcnt(2), raw s_barrier;
// vmcnt(0) only last iteration. Grid: 896 blocks (56 chunks/head, <=16
// key-tiles each), fid%8==head%8 XCD affinity.
__global__ __launch_bounds__(256) void attn_kernel(
    const unsigned short* __restrict__ qb, const unsigned short* __restrict__ kb,
    const unsigned short* __restrict__ vt,
    unsigned short* __restrict__ o_part, float* __restrict__ l_part) {
  __shared__ alignas(16) unsigned short Ks[2][64 * 64];
  __shared__ alignas(16) unsigned short Vs[2][64 * 64];
  __shared__ alignas(16) __bf16 p_lds[4][32][72];
  const int fid = blockIdx.x;  // 0..895
  const int h = (fid & 7) + ((fid >= 448) ? 8 : 0);
  const int g = (fid >> 3) - ((fid >= 448) ? 56 : 0);  // 0..55
  int x, c;
  if (g < 24) { x = g / 3; c = g - 3 * x; }
  else { int g2 = g - 24; x = 8 + (g2 >> 2); c = g2 & 3; }

  const int tid = threadIdx.x;
  const int w = tid >> 6;
  const int lane = tid & 63;
  const int lr = lane & 15;
  const int lg = lane >> 4;
  const int qb0 = x * 128;
  const int q0 = qb0 + w * 32;

  const unsigned short* qr0 = qb + (size_t)(q0 + lr) * E_DIM + h * HDIM + lg * 8;
  const unsigned short* qr1 = qb + (size_t)(q0 + 16 + lr) * E_DIM + h * HDIM + lg * 8;
  const bf16x8 qf00 = *reinterpret_cast<const bf16x8*>(qr0);
  const bf16x8 qf01 = *reinterpret_cast<const bf16x8*>(qr0 + 32);
  const bf16x8 qf10 = *reinterpret_cast<const bf16x8*>(qr1);
  const bf16x8 qf11 = *reinterpret_cast<const bf16x8*>(qr1 + 32);

  const unsigned short* kh = kb + (size_t)h * T_LEN * HDIM;
  const unsigned short* vh = vt + (size_t)h * HDIM * T_LEN;

  const int srow = tid >> 3;  // 0..31
  const int sseg = (tid & 7) ^ (srow & 7);
  const unsigned short* ksrc = kh + (size_t)srow * HDIM + sseg * 8;
  const unsigned short* vsrc = vh + (size_t)srow * T_LEN + sseg * 8;

  f32x4 o[2][4];
  float lsum[2][2];
#pragma unroll
  for (int sb = 0; sb < 2; ++sb) {
    lsum[sb][0] = lsum[sb][1] = 0.f;
#pragma unroll
    for (int jd = 0; jd < 4; ++jd) o[sb][jd] = f32x4{0.f, 0.f, 0.f, 0.f};
  }

  const int jmaxq = q0 + PASTL;
  const int NTfull = 34 + 2 * x;
  const int tb = c * 16;
  const int te = (tb + 16 < NTfull) ? tb + 16 : NTfull;
  const int NT = te - tb;   // >= 2
  const int tbeg = tb * 64;

  auto stageK = [&](int b, int t0) {
    GLOBAL_LOAD_LDS16(ksrc + (size_t)t0 * HDIM, (char*)Ks[b] + tid * 16);
    GLOBAL_LOAD_LDS16(ksrc + (size_t)(t0 + 32) * HDIM, (char*)Ks[b] + 4096 + tid * 16);
  };
  auto stageV = [&](int b, int t0) {
    GLOBAL_LOAD_LDS16(vsrc + t0, (char*)Vs[b] + tid * 16);
    GLOBAL_LOAD_LDS16(vsrc + t0 + (size_t)32 * T_LEN, (char*)Vs[b] + 4096 + tid * 16);
  };

  stageK(0, tbeg);
  stageV(0, tbeg);
  int cur = 0;
  int t0 = tbeg;
  for (int i = 0; i < NT; ++i, t0 += 64) {
    const bool more = (i + 1 < NT);
    // ---- phase 1: K ready (this tile's V still in flight) ----
    asm volatile("s_waitcnt vmcnt(2)" ::: "memory");
    __builtin_amdgcn_s_barrier();
    __builtin_amdgcn_sched_barrier(0);
    if (more) stageK(cur ^ 1, t0 + 64);

    bf16x8 kf[4][2];
#pragma unroll
    for (int j = 0; j < 4; ++j) {
      int row = j * 16 + lr;
      int s0 = lg ^ (row & 7), s1 = (4 + lg) ^ (row & 7);
      kf[j][0] = *reinterpret_cast<const bf16x8*>((const char*)Ks[cur] + row * 128 + s0 * 16);
      kf[j][1] = *reinterpret_cast<const bf16x8*>((const char*)Ks[cur] + row * 128 + s1 * 16);
    }

    f32x4 sc[2][4];
#pragma unroll
    for (int sb = 0; sb < 2; ++sb)
#pragma unroll
      for (int j = 0; j < 4; ++j) sc[sb][j] = f32x4{0.f, 0.f, 0.f, 0.f};
    __builtin_amdgcn_s_setprio(1);
#pragma unroll
    for (int j = 0; j < 4; ++j) {
      sc[0][j] = mfma_bf16(kf[j][0], qf00, sc[0][j]);
      sc[0][j] = mfma_bf16(kf[j][1], qf01, sc[0][j]);
      sc[1][j] = mfma_bf16(kf[j][0], qf10, sc[1][j]);
      sc[1][j] = mfma_bf16(kf[j][1], qf11, sc[1][j]);
    }
    __builtin_amdgcn_s_setprio(0);

    // ---- softmax -> p_lds (per-wave private; no barrier needed) ----
    const bool partial = (t0 + 63 > jmaxq);
    const int thr = q0 + PASTL - t0 + lr;
    const int lg4 = lg * 4;
#pragma unroll
    for (int sb = 0; sb < 2; ++sb) {
#pragma unroll
      for (int j = 0; j < 4; ++j) {
        bf16x4 pk;
#pragma unroll
        for (int r = 0; r < 4; ++r) {
          float p = __builtin_amdgcn_exp2f(sc[sb][j][r]);
          if (partial && (j * 16 + lg4 + r > thr + sb * 16)) p = 0.f;
          lsum[sb][r >> 1] += p;
          pk[r] = (__bf16)p;
        }
        *reinterpret_cast<bf16x4*>(&p_lds[w][sb * 16 + lr][j * 16 + lg4]) = pk;
      }
    }
    bf16x8 pa[2][2];
#pragma unroll
    for (int sb = 0; sb < 2; ++sb) {
      pa[sb][0] = *reinterpret_cast<const bf16x8*>(&p_lds[w][sb * 16 + lr][lg * 8]);
      pa[sb][1] = *reinterpret_cast<const bf16x8*>(&p_lds[w][sb * 16 + lr][32 + lg * 8]);
    }

    // ---- phase 2: V ready (next K in flight) ----
    if (more) {
      asm volatile("s_waitcnt vmcnt(2)" ::: "memory");
    } else {
      asm volatile("s_waitcnt vmcnt(0)" ::: "memory");
    }
    __builtin_amdgcn_s_barrier();
    __builtin_amdgcn_sched_barrier(0);
    if (more) stageV(cur ^ 1, t0 + 64);

    __builtin_amdgcn_s_setprio(1);
#pragma unroll
    for (int jd = 0; jd < 4; ++jd) {
      int row = jd * 16 + lr;
      int s0 = lg ^ (row & 7), s1 = (4 + lg) ^ (row & 7);
      bf16x8 vf0 = *reinterpret_cast<const bf16x8*>((const char*)Vs[cur] + row * 128 + s0 * 16);
      bf16x8 vf1 = *reinterpret_cast<const bf16x8*>((const char*)Vs[cur] + row * 128 + s1 * 16);
      o[0][jd] = mfma_bf16(pa[0][0], vf0, o[0][jd]);
      o[0][jd] = mfma_bf16(pa[0][1], vf1, o[0][jd]);
      o[1][jd] = mfma_bf16(pa[1][0], vf0, o[1][jd]);
      o[1][jd] = mfma_bf16(pa[1][1], vf1, o[1][jd]);
    }
    __builtin_amdgcn_s_setprio(0);
    cur ^= 1;
  }

  // partials: o_part[c][h][row][d] bf16, l_part[c][h][row] f32
  unsigned short* op = o_part + ((size_t)(c * NHEAD + h) * S_LEN) * HDIM;
  float* lp = l_part + (size_t)(c * NHEAD + h) * S_LEN;
#pragma unroll
  for (int sb = 0; sb < 2; ++sb) {
    float ls = lsum[sb][0] + lsum[sb][1];
    ls += __shfl_xor(ls, 16);
    ls += __shfl_xor(ls, 32);
    if (lg == 0) lp[q0 + sb * 16 + lr] = ls;
#pragma unroll
    for (int jd = 0; jd < 4; ++jd) {
#pragma unroll
      for (int r = 0; r < 4; ++r) {
        int row = q0 + sb * 16 + lg * 4 + r;
        op[(size_t)row * HDIM + jd * 16 + lr] = f2bf(o[sb][jd][r]);
      }
    }
  }
}

// Merge chunk partials (3 for rows<1024, 4 otherwise) and normalize -> ab bf16.
__global__ __launch_bounds__(256) void attn_merge_kernel(
    const unsigned short* __restrict__ o_part, const float* __restrict__ l_part,
    unsigned short* __restrict__ ab) {
  const int flat = blockIdx.x * 256 + threadIdx.x;
  const int d4 = flat & 15;
  const int row = (flat >> 4) & (S_LEN - 1);
  const int h = flat >> 15;
  const int nc = (row < 1024) ? 3 : 4;
  const size_t cstride_o = (size_t)NHEAD * S_LEN * HDIM;
  const size_t base_o = (((size_t)h * S_LEN) + row) * HDIM + d4 * 4;
  float acc[4] = {0.f, 0.f, 0.f, 0.f};
  float l = 0.f;
  for (int cc = 0; cc < nc; ++cc) {
    ushort4 u = *(const ushort4*)(o_part + cc * cstride_o + base_o);
    acc[0] += bf2f(u.x); acc[1] += bf2f(u.y);
    acc[2] += bf2f(u.z); acc[3] += bf2f(u.w);
    l += l_part[(size_t)cc * NHEAD * S_LEN + (size_t)h * S_LEN + row];
  }
  float inv = 1.f / l;
  ushort4 u;
  u.x = f2bf(acc[0] * inv);
  u.y = f2bf(acc[1] * inv);
  u.z = f2bf(acc[2] * inv);
  u.w = f2bf(acc[3] * inv);
  *(ushort4*)(ab + (size_t)row * E_DIM + h * HDIM + d4 * 4) = u;
}

// ---------------------------------------------------------------- launch

extern "C" void kernel_launch(void* const* d_in, const int* in_sizes, int n_in,
                              void* d_out, int out_size, void* d_ws, size_t ws_size,
                              hipStream_t stream) {
  (void)in_sizes; (void)n_in; (void)out_size; (void)ws_size;
  const float* x    = (const float*)d_in[0];
  const float* past = (const float*)d_in[1];
  const float* W1   = (const float*)d_in[2];
  const float* b1   = (const float*)d_in[3];
  const float* W2   = (const float*)d_in[4];
  const float* b2   = (const float*)d_in[5];

  float* out = (float*)d_out;
  float* cache_k = out + (size_t)S_LEN * E_DIM;
  float* cache_v = cache_k + (size_t)NHEAD * T_LEN * HDIM;

  // Workspace layout (42.5 MiB peak), lifetime-disjoint overlaps:
  //   [0,2)   w2t ; [2,6) qb ; [6,14) kb ; [14,22) vtb
  //   [22,26) xb -> ab ; [26,32) w1t -> o_part ; [26,42) o_part
  //   [42,42.5) l_part
  char* ws = (char*)d_ws;
  unsigned short* w2t = (unsigned short*)(ws);
  unsigned short* qb  = (unsigned short*)(ws + (size_t)(2u  << 20));
  unsigned short* kb  = (unsigned short*)(ws + (size_t)(6u  << 20));
  unsigned short* vtb = (unsigned short*)(ws + (size_t)(14u << 20));
  unsigned short* xb  = (unsigned short*)(ws + (size_t)(22u << 20));
  unsigned short* ab  = (unsigned short*)(ws + (size_t)(22u << 20));  // reuse xb
  unsigned short* w1t = (unsigned short*)(ws + (size_t)(26u << 20));
  unsigned short* o_part = (unsigned short*)(ws + (size_t)(26u << 20));  // reuse w1t
  float* l_part = (float*)(ws + (size_t)(42u << 20));

  prep_kernel<<<3584, 256, 0, stream>>>(past, x, W1, W2, cache_k, kb, xb, w1t,
                                        w2t, vtb);
  gemm_bt_kernel<0><<<768, 256, 0, stream>>>(
      xb, w1t, b1, 1024, nullptr, qb, cache_k, cache_v, kb, vtb);
  attn_kernel<<<dim3(896), 256, 0, stream>>>(qb, kb, vtb, o_part, l_part);
  attn_merge_kernel<<<(NHEAD * S_LEN * 16) / 256, 256, 0, stream>>>(o_part, l_part, ab);
  gemm_bt_kernel<1><<<256, 256, 0, stream>>>(
      ab, w2t, b2, 1024, out, nullptr, nullptr, nullptr, nullptr, nullptr);
}